// Round 3
// baseline (292.664 us; speedup 1.0000x reference)
//
#include <hip/hip_runtime.h>

// NearestEmbed: x (32,64,64,64) f32, weight (64,512) f32.
// Output 0: quantized (32,64,64,64) f32 = weight[:, argmin] scattered back.
// Output 1: argmin (32,64,64) written as float (harness reads whole buffer as f32).
//
// Strategy: one thread per (b,h,w) location. x vector in 64 VGPRs.
// Weight staged in LDS (4 chunks of 64x128 f32 = 32KB), broadcast-read by all
// lanes (same addr -> conflict-free). FP32 main pass with top-3 tracking;
// ambiguous locations (gap < TAU) re-scored in fp64 to match the reference
// argmin exactly.

#define BB   32
#define DD   64
#define HWSZ 4096            // H*W
#define NLOC (BB * HWSZ)     // 131072
#define KK   512
#define KC   128             // k-chunk staged in LDS
#define TAU  1e-3f

__global__ __launch_bounds__(256, 2)
void ne_kernel(const float* __restrict__ x, const float* __restrict__ w,
               float* __restrict__ out_res, float* __restrict__ out_idx) {
    __shared__ float wlds[DD][KC];   // 32 KB
    __shared__ float w2lds[KK];      // 2 KB

    const int tid = threadIdx.x;
    const int loc = blockIdx.x * 256 + tid;
    const int b   = loc >> 12;        // / 4096
    const int hw  = loc & 4095;
    const long base = (long)b * (DD * HWSZ) + hw;

    // ---- load this location's x vector into registers (coalesced per d) ----
    float xr[DD];
    #pragma unroll
    for (int d = 0; d < DD; ++d) xr[d] = x[base + (long)d * HWSZ];

    // ---- precompute ||e_k||^2 into LDS (each thread does 2 k's, coalesced) ----
    #pragma unroll 1
    for (int k = tid; k < KK; k += 256) {
        float s = 0.f;
        #pragma unroll
        for (int d = 0; d < DD; ++d) { float v = w[d * KK + k]; s = fmaf(v, v, s); }
        w2lds[k] = s;
    }
    __syncthreads();

    // ---- main fp32 pass: top-3 score tracking ----
    float s1 = 3.4e38f, s2 = 3.4e38f, s3 = 3.4e38f;
    int   k1 = 0, k2 = 0, k3 = 0;

    #pragma unroll 1
    for (int c = 0; c < KK / KC; ++c) {
        __syncthreads();   // protect wlds from previous chunk's readers
        // stage chunk c: weight[d][c*KC .. c*KC+KC) -> wlds
        #pragma unroll
        for (int i = 0; i < (DD * KC / 4) / 256; ++i) {  // 8 float4 per thread
            int idx = i * 256 + tid;                     // 0..2047
            int d   = idx >> 5;                          // 32 float4 per row
            int c4  = idx & 31;
            float4 v = *(const float4*)(w + d * KK + c * KC + c4 * 4);
            *(float4*)(&wlds[d][c4 * 4]) = v;
        }
        __syncthreads();

        #pragma unroll 1
        for (int kg = 0; kg < KC; kg += 4) {
            float a0 = 0.f, a1 = 0.f, a2 = 0.f, a3 = 0.f;
            #pragma unroll
            for (int d = 0; d < DD; ++d) {
                float4 wv = *(const float4*)(&wlds[d][kg]);   // broadcast read
                a0 = fmaf(xr[d], wv.x, a0);
                a1 = fmaf(xr[d], wv.y, a1);
                a2 = fmaf(xr[d], wv.z, a2);
                a3 = fmaf(xr[d], wv.w, a3);
            }
            const int kb = c * KC + kg;
            float sc0 = fmaf(-2.f, a0, w2lds[kb + 0]);
            float sc1 = fmaf(-2.f, a1, w2lds[kb + 1]);
            float sc2 = fmaf(-2.f, a2, w2lds[kb + 2]);
            float sc3 = fmaf(-2.f, a3, w2lds[kb + 3]);
            float scs[4] = { sc0, sc1, sc2, sc3 };
            #pragma unroll
            for (int j = 0; j < 4; ++j) {
                float s = scs[j]; int kk = kb + j;
                bool b1 = s < s1, b2 = s < s2, b3 = s < s3;
                s3 = b2 ? s2 : (b3 ? s  : s3);
                k3 = b2 ? k2 : (b3 ? kk : k3);
                s2 = b1 ? s1 : (b2 ? s  : s2);
                k2 = b1 ? k1 : (b2 ? kk : k2);
                s1 = b1 ? s  : s1;
                k1 = b1 ? kk : k1;
            }
        }
    }

    // ---- fp64 rescue for ambiguous argmins (rare: ~1e-3 of threads) ----
    if (s2 - s1 < TAU) {
        double bd = 1e300; int bk = 1 << 30;
        #pragma unroll
        for (int ci = 0; ci < 3; ++ci) {
            int kk = (ci == 0) ? k1 : (ci == 1) ? k2 : ((s3 - s1 < TAU) ? k3 : -1);
            if (kk >= 0) {
                double dot = 0.0, w2d = 0.0;
                #pragma unroll
                for (int d = 0; d < DD; ++d) {
                    double wv = (double)w[d * KK + kk];
                    dot = fma((double)xr[d], wv, dot);
                    w2d = fma(wv, wv, w2d);
                }
                double scd = fma(-2.0, dot, w2d);
                if (scd < bd || (scd == bd && kk < bk)) { bd = scd; bk = kk; }
            }
        }
        k1 = bk;
    }

    // ---- outputs ----
    out_idx[loc] = (float)k1;                       // argmin as float
    #pragma unroll
    for (int d = 0; d < DD; ++d)
        out_res[base + (long)d * HWSZ] = w[d * KK + k1];  // gather (L1/L2-hot row)
}

extern "C" void kernel_launch(void* const* d_in, const int* in_sizes, int n_in,
                              void* d_out, int out_size, void* d_ws, size_t ws_size,
                              hipStream_t stream) {
    const float* x = (const float*)d_in[0];
    const float* w = (const float*)d_in[1];
    float* out = (float*)d_out;
    float* out_res = out;                   // 32*64*64*64 = 8388608 floats
    float* out_idx = out + (NLOC * DD);     // 131072 floats (argmin)
    ne_kernel<<<NLOC / 256, 256, 0, stream>>>(x, w, out_res, out_idx);
}